// Round 9
// baseline (12998.972 us; speedup 1.0000x reference)
//
#include <hip/hip_runtime.h>
#include <hip/hip_bf16.h>

typedef __attribute__((ext_vector_type(4))) float floatx4;
typedef __attribute__((ext_vector_type(2))) float floatx2;
typedef __attribute__((ext_vector_type(8))) short shortx8;

#define NB 64
#define NS 256
#define NU 1024
#define NT 512

__device__ __forceinline__ unsigned short f2bf(float f){
  union{float f;unsigned u;}v; v.f=f;
  unsigned r = v.u + 0x7fffu + ((v.u>>16)&1u);
  return (unsigned short)(r>>16);
}
__device__ __forceinline__ float bf2f(unsigned short h){
  union{unsigned u;float f;}v; v.u = ((unsigned)h)<<16; return v.f;
}
__device__ __forceinline__ float sigf(float x){
  return __builtin_amdgcn_rcpf(1.f + __expf(-x));
}

// ---- coherent (LLC-level, fence-free) access helpers -----------------------
// sc0 sc1 loads/stores bypass L1/L2 and serialize at the Infinity-Cache
// coherence point. Used ONLY for the rotating (non-t-indexed) buffers:
// qbuf, watt, gates reads + all cross-block stores. The big A-operand reads
// are plain cached loads of t-indexed buffers (write-once -> stale-free).
__device__ __forceinline__ floatx4 cld_f32x4(const float* p){
  floatx4 v;
  asm volatile("global_load_dwordx4 %0, %1, off sc0 sc1\n\ts_waitcnt vmcnt(0)"
               : "=&v"(v) : "v"(p) : "memory");
  return v;
}
__device__ __forceinline__ void cburst4d2(floatx2 o[4], const float* p0, const float* p1,
                                          const float* p2, const float* p3){
  asm volatile(
    "global_load_dwordx2 %0, %4, off sc0 sc1\n\t"
    "global_load_dwordx2 %1, %5, off sc0 sc1\n\t"
    "global_load_dwordx2 %2, %6, off sc0 sc1\n\t"
    "global_load_dwordx2 %3, %7, off sc0 sc1\n\t"
    "s_waitcnt vmcnt(0)"
    : "=&v"(o[0]),"=&v"(o[1]),"=&v"(o[2]),"=&v"(o[3])
    : "v"(p0),"v"(p1),"v"(p2),"v"(p3) : "memory");
}
__device__ __forceinline__ float cld_f32(const float* p){
  float v;
  asm volatile("global_load_dword %0, %1, off sc0 sc1\n\ts_waitcnt vmcnt(0)"
               : "=&v"(v) : "v"(p) : "memory");
  return v;
}
__device__ __forceinline__ void cst_u16(unsigned short* p, unsigned short v){
  asm volatile("global_store_short %0, %1, off sc0 sc1" :: "v"(p), "v"((unsigned)v) : "memory");
}
__device__ __forceinline__ void cst_f32(float* p, float v){
  asm volatile("global_store_dword %0, %1, off sc0 sc1" :: "v"(p), "v"(v) : "memory");
}
__device__ __forceinline__ void cst_u32(unsigned* p, unsigned v){
  asm volatile("global_store_dword %0, %1, off sc0 sc1" :: "v"(p), "v"(v) : "memory");
}

// ---------------------------------------------------------------------------
// Generic bf16 MFMA GEMM (prep/epilogue; unchanged - known correct).
// ---------------------------------------------------------------------------
template<int MODE>
__global__ void gemm_sw(const unsigned short* __restrict__ A,
                        const unsigned short* __restrict__ Bsw,
                        void* __restrict__ Cout,
                        int M, int N, int K, int ldc,
                        const float* __restrict__ bias)
{
  const int lane = threadIdx.x & 63;
  const int lm = lane & 15, quad = lane >> 4;
  const int nwaves = (gridDim.x * blockDim.x) >> 6;
  const int w = (blockIdx.x * blockDim.x + threadIdx.x) >> 6;
  const int m64 = M >> 6, n64 = N >> 6, KS = K >> 5;
  const int ntask = m64 * n64;
  for (int task = w; task < ntask; task += nwaves) {
    const int mt = task % m64, nt = task / m64;
    floatx4 acc[4][4];
#pragma unroll
    for (int i=0;i<4;i++)
#pragma unroll
      for(int j=0;j<4;j++) acc[i][j] = (floatx4){0.f,0.f,0.f,0.f};
    const unsigned short* Ab = A + (size_t)(mt*64 + lm) * K + quad*8;
    for (int ks=0; ks<KS; ++ks) {
      shortx8 a[4], b[4];
#pragma unroll
      for (int i=0;i<4;i++)
        a[i] = *(const shortx8*)(Ab + (size_t)i*16*K + ks*32);
#pragma unroll
      for (int j=0;j<4;j++)
        b[j] = *(const shortx8*)(Bsw + (((size_t)(nt*4+j)*KS + ks)*64 + lane)*8);
#pragma unroll
      for (int i=0;i<4;i++)
#pragma unroll
        for (int j=0;j<4;j++)
          acc[i][j] = __builtin_amdgcn_mfma_f32_16x16x32_bf16(a[i], b[j], acc[i][j], 0,0,0);
    }
#pragma unroll
    for (int i=0;i<4;i++){
#pragma unroll
      for (int j=0;j<4;j++){
        const int col = nt*64 + j*16 + lm;
        const float bv = bias ? bias[col] : 0.f;
#pragma unroll
        for (int r=0;r<4;r++){
          const int row = mt*64 + i*16 + quad*4 + r;
          const float v = acc[i][j][r] + bv;
          if (MODE==0)      ((float*)Cout)[(size_t)row*ldc + col] = v;
          else if (MODE==1) ((unsigned short*)Cout)[(size_t)row*ldc + col] = f2bf(v);
          else { const int orow = (row&63)*NS + (row>>6);
                 ((float*)Cout)[(size_t)orow*ldc + col] = v; }
        }
      }
    }
  }
}

// ---- prep kernels (unchanged) ---------------------------------------------
__global__ void conv_h(const float* __restrict__ src, unsigned short* __restrict__ dst, int n){
  for (int i = blockIdx.x*blockDim.x + threadIdx.x; i < n; i += gridDim.x*blockDim.x)
    dst[i] = f2bf(src[i]);
}

__global__ void conv_misc(const float* __restrict__ Wy2, const float* __restrict__ We2,
                          const float* __restrict__ s0, const float* __restrict__ by1,
                          const float* __restrict__ be1,
                          unsigned short* __restrict__ Wy2A, unsigned short* __restrict__ we2b,
                          unsigned short* __restrict__ s_bf, float* __restrict__ bz)
{
  int i = blockIdx.x*blockDim.x + threadIdx.x;
  if (i < 524288) Wy2A[i] = f2bf(Wy2[i]);
  else if (i < 525312) we2b[i-524288] = f2bf(We2[i-524288]);
  else if (i < 590848) s_bf[i-525312] = f2bf(s0[i-525312]);
  else if (i < 592896) { int n = i - 590848; bz[n] = (n<1024)? by1[n] : be1[n-1024]; }
}

__global__ void vbias_k(const float* __restrict__ by2,
                        const float* __restrict__ bi, const float* __restrict__ bff,
                        const float* __restrict__ bg, const float* __restrict__ bo,
                        const float* __restrict__ Wi, const float* __restrict__ Wf,
                        const float* __restrict__ Wg, const float* __restrict__ Wo,
                        float* __restrict__ vb)
{
  int i = blockIdx.x*blockDim.x + threadIdx.x;
  if (i >= 4096) return;
  int g = i >> 10, u = i & 1023;
  const float* bsrc = (g==0)?bi:(g==1)?bff:(g==2)?bg:bo;
  const float* W    = (g==0)?Wi:(g==1)?Wf:(g==2)?Wg:Wo;
  float s = bsrc[u];
  for (int tt = 0; tt < NT; ++tt) s += by2[tt] * W[(size_t)tt*NU + u];
  vb[i] = s;
}

__global__ void pack_b(const float* __restrict__ src, unsigned short* __restrict__ dst, int K, int N)
{
  const int KS = K >> 5;
  const size_t total = (size_t)K * N;
  for (size_t i = (size_t)blockIdx.x*blockDim.x + threadIdx.x; i < total;
       i += (size_t)gridDim.x*blockDim.x) {
    int j = i & 7; int lane = (i>>3) & 63; int r = (int)(i >> 9);
    int ks = r % KS; int nt = r / KS;
    int k = ks*32 + (lane>>4)*8 + j;
    int n = nt*16 + (lane&15);
    dst[i] = f2bf(src[(size_t)k*N + n]);
  }
}

__global__ void pack_a1(const float* __restrict__ Wy1, const float* __restrict__ We1,
                        unsigned short* __restrict__ dst)
{
  const int KS = 32;
  const size_t total = (size_t)1024*2048;
  for (size_t i = (size_t)blockIdx.x*blockDim.x + threadIdx.x; i < total;
       i += (size_t)gridDim.x*blockDim.x) {
    int j = i & 7; int lane = (i>>3) & 63; int r = (int)(i >> 9);
    int ks = r % KS; int nt = r / KS;
    int k = ks*32 + (lane>>4)*8 + j;
    int n = nt*16 + (lane&15);
    float v = (n < 1024) ? Wy1[(size_t)k*1024 + n]
                         : We1[(size_t)(1024+k)*1024 + (n-1024)];
    dst[i] = f2bf(v);
  }
}

__global__ void pack_wbig(const float* __restrict__ Mg,
                          const float* __restrict__ Wi, const float* __restrict__ Wf,
                          const float* __restrict__ Wg, const float* __restrict__ Wo,
                          unsigned short* __restrict__ dst)
{
  const int KS = 64;
  const size_t total = (size_t)2048*4096;
  for (size_t i = (size_t)blockIdx.x*blockDim.x + threadIdx.x; i < total;
       i += (size_t)gridDim.x*blockDim.x) {
    int j = i & 7; int lane = (i>>3) & 63; int r = (int)(i >> 9);
    int ks = r % KS; int nt = r / KS;
    int k = ks*32 + (lane>>4)*8 + j;
    int n = nt*16 + (lane&15);
    int g = n >> 10, u = n & 1023;
    float v;
    if (k < 1024) v = Mg[(size_t)g*1048576 + (size_t)k*1024 + u];
    else {
      const float* W = (g==0)?Wi:(g==1)?Wf:(g==2)?Wg:Wo;
      v = W[(size_t)(512 + k - 1024)*1024 + u];
    }
    dst[i] = f2bf(v);
  }
}

// ---- the sequential recurrence: persistent kernel, FENCE-FREE barrier ------
// v9 = v5 (verified best) + ONE addition: during P1 (where waves 8..15 were
// idle), those waves issue plain cached reads over the block's Wbig slice
// (64 KB) to pre-fill L2, so P2's gates-GEMM B-reads become warm hits.
// Values are kept live via empty asm (prevents DCE); no numerics change.
// R6/R7/R8's remap/LDS/dedup variants are all REVERTED (each regressed).
struct LoopArgs {
  unsigned short* s_all;         // (257,64,1024) bf16 t-indexed state
  unsigned short* tanh_all;      // (256,64,1024) bf16 t-indexed
  const unsigned short* A1_sw;   // weights [cached]
  const unsigned short* Wbig_sw; // weights [cached, P1-prefetched into L2]
  const unsigned short* hproj;   // (64,256,1024) bf16  [staged to LDS pre-loop]
  const float* h;                // input h f32         [staged to VGPRs pre-loop]
  const unsigned short* we2b;    // (1024) bf16 [cached]
  float* qbuf;                   // (64,1024)   rotating [coherent]
  float* watt;                   // (64,256)    rotating [coherent]
  float* gates;                  // (64,4096)   rotating [coherent]
  const float* bz;               // (2048) [cached]
  const float* vbias;            // (4096) [cached]
  const float* be2;              // (1) [cached]
  int* bar;                      // barrier state, zeroed
};

__global__ void __launch_bounds__(1024) loop_kernel(LoopArgs A)
{
  const int tid = threadIdx.x;
  const int bid = blockIdx.x;                 // 256 blocks
  const int wid = tid >> 6;                   // 0..15
  const int lane = tid & 63;
  const int lm = lane & 15, quad = lane >> 4;

  // 128 KiB dynamic LDS: this block's hproj slice (loop-invariant).
  extern __shared__ floatx4 dynlds_v4[];
  unsigned char* const dynlds = (unsigned char*)dynlds_v4;

  // barrier layout (128B-strided counters): gcnt[16], root, gen
  int* gcnt = A.bar;
  int* root = A.bar + 16*32;
  int* genp = A.bar + 16*32 + 32;

  __shared__ float qsh[1024];        // 4 KB: this step's q for batch b3
  __shared__ floatx4 pbuf[256];      // 4 KB: K-split partial accumulators
  __shared__ float wsh[256];
  __shared__ float zparts[4];
  __shared__ floatx2 cbuf[1024];     // 8 KB

  auto gsync = [&]() {
    asm volatile("s_waitcnt vmcnt(0) lgkmcnt(0)" ::: "memory");
    __syncthreads();
    if (tid == 0) {
      int g = __hip_atomic_load(genp, __ATOMIC_RELAXED, __HIP_MEMORY_SCOPE_AGENT);
      int grp = bid >> 4;
      if (__hip_atomic_fetch_add(&gcnt[grp*32], 1, __ATOMIC_RELAXED, __HIP_MEMORY_SCOPE_AGENT) == 15) {
        __hip_atomic_store(&gcnt[grp*32], 0, __ATOMIC_RELAXED, __HIP_MEMORY_SCOPE_AGENT);
        if (__hip_atomic_fetch_add(root, 1, __ATOMIC_RELAXED, __HIP_MEMORY_SCOPE_AGENT) == 15) {
          __hip_atomic_store(root, 0, __ATOMIC_RELAXED, __HIP_MEMORY_SCOPE_AGENT);
          __hip_atomic_store(genp, g + 1, __ATOMIC_RELAXED, __HIP_MEMORY_SCOPE_AGENT);
        }
      }
      while (__hip_atomic_load(genp, __ATOMIC_RELAXED, __HIP_MEMORY_SCOPE_AGENT) == g)
        __builtin_amdgcn_s_sleep(1);
    }
    __syncthreads();
  };

  // -------- pre-loop staging: h and hproj are LOOP-INVARIANT ---------------
  const int b3 = bid >> 2;
  const int j0_blk = (bid & 3) << 6;
  const int u3 = ((bid & 3) << 8) + (tid & 127) * 2;
  const int js3 = (tid >> 7) << 5;           // 8 j-groups x 32 rows

  unsigned hreg[32];                 // h[b3, js3+jj, u3:u3+2] packed bf16x2
  {
    const float* hb = A.h + (size_t)b3*NS*NU;
#pragma unroll
    for (int jj = 0; jj < 32; ++jj) {
      const floatx2 hv = *(const floatx2*)(hb + (size_t)(js3 + jj)*NU + u3);
      hreg[jj] = ((unsigned)f2bf(hv[0])) | (((unsigned)f2bf(hv[1])) << 16);
    }
  }
  {
    // hproj[b3, j0_blk .. j0_blk+64, :] -> LDS, row r at dynlds + r*2048
    const unsigned char* hpg = (const unsigned char*)(A.hproj + ((size_t)(b3*NS + j0_blk))*NU);
#pragma unroll
    for (int it = 0; it < 8; ++it)
      *(floatx4*)(dynlds + it*16384 + tid*16) = *(const floatx4*)(hpg + it*16384 + tid*16);
  }
  // attention constants: lane's u-window split-half {8l..8l+7, 512+8l..+7}
  float w2r[16];
  if (wid >= 8) {
    const shortx8 wa = *(const shortx8*)(A.we2b + 8*lane);
    const shortx8 wb = *(const shortx8*)(A.we2b + 512 + 8*lane);
#pragma unroll
    for (int i = 0; i < 8; ++i) {
      w2r[i]   = bf2f((unsigned short)wa[i]);
      w2r[8+i] = bf2f((unsigned short)wb[i]);
    }
  }
  const float be2v = A.be2[0];
  __syncthreads();

#pragma clang loop unroll(disable)
  for (int t = 0; t < NS; ++t) {
    const unsigned short* sbase = A.s_all + (size_t)t*(NB*NU);
    // -------- P1: z2 = s @ [Wy1|We1_s] + bz -> tanh1 (bf16), q (fp32)
    // K-split over 4 waves (v5 mapping); waves 8..15 prefetch the block's
    // Wbig slice (64 KB) into L2 so P2's B-reads are warm hits.
    {
      floatx4 accg = (floatx4){0.f,0.f,0.f,0.f};
      if (wid < 4) {
        const int task = bid*2 + (wid & 1);
        const int mt = task & 3, nt = task >> 2;
        const int kh = wid >> 1;
        floatx4 acc = (floatx4){0.f,0.f,0.f,0.f};
        const unsigned short* Ab = sbase + (mt*16 + lm)*NU + quad*8;
        for (int k = 0; k < 2; ++k) {
          const int kb = kh*2 + k;
          shortx8 a[8];
#pragma unroll
          for (int q = 0; q < 8; ++q) a[q] = *(const shortx8*)(Ab + kb*256 + q*32);
#pragma unroll
          for (int q = 0; q < 8; ++q) {
            shortx8 b = *(const shortx8*)(A.A1_sw + (((size_t)nt*32 + kb*8 + q)*64 + lane)*8);
            acc = __builtin_amdgcn_mfma_f32_16x16x32_bf16(a[q], b, acc, 0,0,0);
          }
        }
        if (wid >= 2) pbuf[(wid-2)*64 + lane] = acc; else accg = acc;
      } else if (wid >= 8) {
        // L2 prefetch: Wbig slice nt=bid = 64 KB = 4096 floatx4.
        // 8 waves x 8 iters x 64 lanes x 16 B. Kept live via empty asm.
        const floatx4* wp = (const floatx4*)A.Wbig_sw
                          + (size_t)bid*4096 + (size_t)(wid-8)*512 + lane;
        float p0 = 0.f, p1 = 0.f, p2 = 0.f, p3 = 0.f;
#pragma unroll
        for (int it = 0; it < 8; ++it) {
          const floatx4 v = wp[it*64];
          p0 += v[0]; p1 += v[1]; p2 += v[2]; p3 += v[3];
        }
        asm volatile("" :: "v"(p0), "v"(p1), "v"(p2), "v"(p3));
      }
      __syncthreads();
      if (wid < 2) {
        const int task = bid*2 + wid;
        const int mt = task & 3, nt = task >> 2;
        floatx4 acc = accg + pbuf[wid*64 + lane];
        const int col = nt*16 + lm;
        const float bzv = A.bz[col];
#pragma unroll
        for (int r = 0; r < 4; ++r) {
          const int row = mt*16 + quad*4 + r;
          const float v = acc[r] + bzv;
          if (col < NU) cst_u16(A.tanh_all + (size_t)t*(NB*NU) + row*NU + col, f2bf(tanhf(v)));
          else          cst_f32(A.qbuf + row*NU + (col - NU), v);
        }
      }
    }
    gsync();
    // -------- P2: gates GEMM (waves 0..7, K-split) || attention (waves 8..15)
    {
      // stage q once per block (kills the x16 qbuf LLC redundancy)
      if (tid >= 512 && tid < 768) {
        const int i = tid - 512;
        *(floatx4*)&qsh[i*4] = cld_f32x4(A.qbuf + b3*NU + i*4);
      }
      __syncthreads();
      floatx4 accg = (floatx4){0.f,0.f,0.f,0.f};
      if (wid < 8) {
        const int mt = wid & 3, nt = bid;
        const int sel = wid >> 2;            // 0: tanh-half, 1: s-half
        floatx4 acc = (floatx4){0.f,0.f,0.f,0.f};
        const int arow = mt*16 + lm;
        const unsigned short* aA =
            (sel ? sbase : A.tanh_all + (size_t)t*(NB*NU)) + arow*NU + quad*8;
        const int bofs = sel ? 32 : 0;
        for (int kb = 0; kb < 4; ++kb) {
          shortx8 a[8];
#pragma unroll
          for (int q = 0; q < 8; ++q) a[q] = *(const shortx8*)(aA + kb*256 + q*32);
#pragma unroll
          for (int q = 0; q < 8; ++q) {
            shortx8 b = *(const shortx8*)(A.Wbig_sw + (((size_t)nt*64 + bofs + kb*8 + q)*64 + lane)*8);
            acc = __builtin_amdgcn_mfma_f32_16x16x32_bf16(a[q], b, acc, 0,0,0);
          }
        }
        if (sel) pbuf[(wid-4)*64 + lane] = acc; else accg = acc;
      } else {
        // attention: 8 rows per wave, hproj from LDS, q from LDS
        const int rbase = (wid - 8) * 8;
        float qv[16];
#pragma unroll
        for (int i = 0; i < 8; ++i) {
          qv[i]   = qsh[8*lane + i];
          qv[8+i] = qsh[512 + 8*lane + i];
        }
        for (int jj = 0; jj < 8; ++jj) {
          const int rl = rbase + jj;
          const shortx8 h0 = *(const shortx8*)(dynlds + rl*2048 + lane*16);
          const shortx8 h1 = *(const shortx8*)(dynlds + rl*2048 + 1024 + lane*16);
          float dot = 0.f;
#pragma unroll
          for (int i = 0; i < 8; ++i) {
            const float x = bf2f((unsigned short)h0[i]) + qv[i];
            dot += w2r[i] * sigf(x);
          }
#pragma unroll
          for (int i = 0; i < 8; ++i) {
            const float x = bf2f((unsigned short)h1[i]) + qv[8+i];
            dot += w2r[8+i] * sigf(x);
          }
#pragma unroll
          for (int off = 32; off > 0; off >>= 1) dot += __shfl_down(dot, off, 64);
          if (lane == 0) {
            const float e = 1.f/(1.f + __expf(-(dot + be2v)));
            cst_f32(A.watt + b3*NS + (j0_blk + rl), __expf(e));
          }
        }
      }
      __syncthreads();
      if (wid < 4) {
        floatx4 acc = accg + pbuf[wid*64 + lane];
        const int col = bid*16 + lm;
        const float vb = A.vbias[col];
#pragma unroll
        for (int r = 0; r < 4; ++r) {
          const int row = (wid&3)*16 + quad*4 + r;
          cst_f32(A.gates + row*4096 + col, acc[r] + vb);
        }
      }
    }
    gsync();
    // -------- P3: softmax-normalize + context c (from hreg) + LSTM -> s_next
    {
      const int b = b3, uc = (bid & 3) << 8;
      if (tid < 256) wsh[tid] = cld_f32(A.watt + b*NS + tid);
      __syncthreads();
      if (wid < 4) {
        float z = wsh[wid*64 + lane];
#pragma unroll
        for (int off = 32; off > 0; off >>= 1) z += __shfl_down(z, off, 64);
        if (lane == 0) zparts[wid] = z;
      }
      __syncthreads();
      const float invZ = __builtin_amdgcn_rcpf(zparts[0]+zparts[1]+zparts[2]+zparts[3]);
      float c0 = 0.f, c1 = 0.f;
#pragma unroll
      for (int jj = 0; jj < 32; ++jj) {
        const unsigned hv = hreg[jj];
        const float wv = wsh[js3 + jj];
        c0 += wv * bf2f((unsigned short)(hv & 0xffffu));
        c1 += wv * bf2f((unsigned short)(hv >> 16));
      }
      cbuf[tid] = (floatx2){c0, c1};
      __syncthreads();
      if (tid < 128) {
        float cc0 = 0.f, cc1 = 0.f;
#pragma unroll
        for (int k = 0; k < 8; ++k) {
          const floatx2 v = cbuf[tid + (k << 7)];
          cc0 += v[0]; cc1 += v[1];
        }
        cc0 *= invZ; cc1 *= invZ;
        const int uu = uc + tid*2;
        const float* gp = A.gates + b*4096;
        floatx2 g4[4];
        cburst4d2(g4, gp + uu, gp + NU + uu, gp + 2*NU + uu, gp + 3*NU + uu);
        unsigned sout = 0;
#pragma unroll
        for (int p = 0; p < 2; ++p) {
          const float cx = p ? cc1 : cc0;
          const float iv = sigf(g4[0][p]);
          const float fv = sigf(g4[1][p]);
          const float gv = tanhf(g4[2][p]);
          const float ov = sigf(g4[3][p]);
          const float cn = fv*cx + iv*gv;
          const float sn = ov * tanhf(cn);
          sout |= ((unsigned)f2bf(sn)) << (16*p);
        }
        cst_u32((unsigned*)(A.s_all + (size_t)(t+1)*(NB*NU) + b*NU + uu), sout);
      }
    }
    gsync();
  }
}

// ---------------------------------------------------------------------------
extern "C" void kernel_launch(void* const* d_in, const int* in_sizes, int n_in,
                              void* d_out, int out_size, void* d_ws, size_t ws_size,
                              hipStream_t stream)
{
  const float* h   = (const float*)d_in[0];
  const float* s0  = (const float*)d_in[1];
  const float* Wy1 = (const float*)d_in[2];
  const float* by1 = (const float*)d_in[3];
  const float* Wy2 = (const float*)d_in[4];
  const float* by2 = (const float*)d_in[5];
  const float* We1 = (const float*)d_in[6];
  const float* be1 = (const float*)d_in[7];
  const float* We2 = (const float*)d_in[8];
  const float* be2 = (const float*)d_in[9];
  const float* Wf_p = (const float*)d_in[10];
  const float* bf_p = (const float*)d_in[11];
  const float* Wi_p = (const float*)d_in[12];
  const float* bi_p = (const float*)d_in[13];
  const float* Wg_p = (const float*)d_in[14];
  const float* bg_p = (const float*)d_in[15];
  const float* Wo_p = (const float*)d_in[16];
  const float* bo_p = (const float*)d_in[17];
  (void)in_sizes; (void)n_in; (void)out_size; (void)ws_size;

  char* ws = (char*)d_ws;
  size_t off = 0;
  auto alloc = [&](size_t bytes)->char*{
    char* p = ws + off; off = (off + bytes + 255) & ~(size_t)255; return p;
  };
  unsigned short* h_bf    = (unsigned short*)alloc((size_t)NB*NS*NU*2);   // 33.5 MB
  unsigned short* hproj   = (unsigned short*)alloc((size_t)NB*NS*NU*2);   // 33.5 MB
  unsigned short* tanh_all= (unsigned short*)alloc((size_t)NS*NB*NU*2);   // 33.5 MB
  unsigned short* s_all   = (unsigned short*)alloc((size_t)(NS+1)*NB*NU*2); // 33.7 MB
  unsigned short* A1_sw   = (unsigned short*)alloc((size_t)NU*2048*2);    // 4.2 MB
  unsigned short* Wbig_sw = (unsigned short*)alloc((size_t)2048*4096*2);  // 16.8 MB
  unsigned short* We1h_sw = (unsigned short*)alloc((size_t)NU*NU*2);      // 2.1 MB
  unsigned short* Wy2_sw  = (unsigned short*)alloc((size_t)NU*NT*2);      // 1.05 MB
  unsigned short* we2b = (unsigned short*)alloc(NU*2);
  float* qbuf  = (float*)alloc((size_t)NB*NU*4);
  float* watt  = (float*)alloc((size_t)NB*NS*4);
  float* gates = (float*)alloc((size_t)NB*4096*4);
  float* bz    = (float*)alloc(2048*4);
  float* vbias = (float*)alloc(4096*4);
  int*   bar   = (int*)alloc(4096);
  // prep-only buffers aliased into regions not yet written at their use time:
  float* Mg = (float*)tanh_all;                    // 16.8 MB, dead before loop
  unsigned short* Wy2A    = hproj;                 // dead before hproj GEMM
  unsigned short* Wgtop_sw= hproj + (size_t)NU*NT; // 4 MB, dead before hproj GEMM

  hipMemsetAsync(bar, 0, 4096, stream);

  conv_h<<<dim3(4096), dim3(256), 0, stream>>>(h, h_bf, NB*NS*NU);
  conv_misc<<<dim3(2316), dim3(256), 0, stream>>>(Wy2, We2, s0, by1, be1, Wy2A, we2b, s_all, bz);
  vbias_k<<<dim3(16), dim3(256), 0, stream>>>(by2, bi_p, bf_p, bg_p, bo_p,
                                              Wi_p, Wf_p, Wg_p, Wo_p, vbias);
  pack_b<<<dim3(1024), dim3(256), 0, stream>>>(We1, We1h_sw, 1024, 1024);   // We1_h
  pack_b<<<dim3(1024), dim3(256), 0, stream>>>(Wy2, Wy2_sw, 1024, 512);
  pack_b<<<dim3(512), dim3(256), 0, stream>>>(Wi_p, Wgtop_sw + 0*((size_t)NT*NU), 512, 1024);
  pack_b<<<dim3(512), dim3(256), 0, stream>>>(Wf_p, Wgtop_sw + 1*((size_t)NT*NU), 512, 1024);
  pack_b<<<dim3(512), dim3(256), 0, stream>>>(Wg_p, Wgtop_sw + 2*((size_t)NT*NU), 512, 1024);
  pack_b<<<dim3(512), dim3(256), 0, stream>>>(Wo_p, Wgtop_sw + 3*((size_t)NT*NU), 512, 1024);
  pack_a1<<<dim3(1024), dim3(256), 0, stream>>>(Wy1, We1, A1_sw);

  // Mg[g] = Wy2 @ W_g[:512]   (M=1024, N=1024, K=512)
  for (int g = 0; g < 4; ++g)
    gemm_sw<0><<<dim3(1024), dim3(256), 0, stream>>>(
        Wy2A, Wgtop_sw + (size_t)g*(NT*NU), Mg + (size_t)g*NU*NU,
        1024, 1024, 512, 1024, nullptr);
  pack_wbig<<<dim3(2048), dim3(256), 0, stream>>>(Mg, Wi_p, Wf_p, Wg_p, Wo_p, Wbig_sw);

  // h_proj = h @ We1_h -> bf16 (M=16384,N=1024,K=1024); overwrites Wy2A/Wgtop region
  gemm_sw<1><<<dim3(1024), dim3(256), 0, stream>>>(
      h_bf, We1h_sw, hproj, NB*NS, 1024, 1024, 1024, nullptr);

  // the 256-step recurrence: persistent kernel, 256 blocks (1/CU), 3 syncs/step
  // 1024 threads/block (16 waves/CU); 128 KiB dynamic LDS = hproj slice
  LoopArgs la;
  la.s_all = s_all; la.tanh_all = tanh_all; la.A1_sw = A1_sw; la.Wbig_sw = Wbig_sw;
  la.hproj = hproj; la.h = h; la.we2b = we2b;
  la.qbuf = qbuf; la.watt = watt; la.gates = gates;
  la.bz = bz; la.vbias = vbias; la.be2 = be2; la.bar = bar;
  loop_kernel<<<dim3(256), dim3(1024), 131072, stream>>>(la);

  // Y = Tanh1_all @ Wy2 + by2, remapped (t,b)->(b,t) into d_out (M=16384,N=512,K=1024)
  gemm_sw<2><<<dim3(1024), dim3(256), 0, stream>>>(
      tanh_all, Wy2_sw, d_out, NB*NS, 512, 1024, 512, by2);
}

// Round 10
// 12267.032 us; speedup vs baseline: 1.0597x; 1.0597x over previous
//
#include <hip/hip_runtime.h>
#include <hip/hip_bf16.h>

typedef __attribute__((ext_vector_type(4))) float floatx4;
typedef __attribute__((ext_vector_type(2))) float floatx2;
typedef __attribute__((ext_vector_type(8))) short shortx8;

#define NB 64
#define NS 256
#define NU 1024
#define NT 512

__device__ __forceinline__ unsigned short f2bf(float f){
  union{float f;unsigned u;}v; v.f=f;
  unsigned r = v.u + 0x7fffu + ((v.u>>16)&1u);
  return (unsigned short)(r>>16);
}
__device__ __forceinline__ float bf2f(unsigned short h){
  union{unsigned u;float f;}v; v.u = ((unsigned)h)<<16; return v.f;
}
__device__ __forceinline__ float sigf(float x){
  return __builtin_amdgcn_rcpf(1.f + __expf(-x));
}

// ---- coherent (LLC-level, fence-free) access helpers -----------------------
// sc0 sc1 loads/stores bypass L1/L2 and serialize at the Infinity-Cache
// coherence point. Used ONLY for the rotating (non-t-indexed) buffers:
// qbuf, watt, gates reads + all cross-block stores. The big A-operand reads
// are plain cached loads of t-indexed buffers (write-once -> stale-free).
__device__ __forceinline__ floatx4 cld_f32x4(const float* p){
  floatx4 v;
  asm volatile("global_load_dwordx4 %0, %1, off sc0 sc1\n\ts_waitcnt vmcnt(0)"
               : "=&v"(v) : "v"(p) : "memory");
  return v;
}
__device__ __forceinline__ void cburst4d2(floatx2 o[4], const float* p0, const float* p1,
                                          const float* p2, const float* p3){
  asm volatile(
    "global_load_dwordx2 %0, %4, off sc0 sc1\n\t"
    "global_load_dwordx2 %1, %5, off sc0 sc1\n\t"
    "global_load_dwordx2 %2, %6, off sc0 sc1\n\t"
    "global_load_dwordx2 %3, %7, off sc0 sc1\n\t"
    "s_waitcnt vmcnt(0)"
    : "=&v"(o[0]),"=&v"(o[1]),"=&v"(o[2]),"=&v"(o[3])
    : "v"(p0),"v"(p1),"v"(p2),"v"(p3) : "memory");
}
__device__ __forceinline__ float cld_f32(const float* p){
  float v;
  asm volatile("global_load_dword %0, %1, off sc0 sc1\n\ts_waitcnt vmcnt(0)"
               : "=&v"(v) : "v"(p) : "memory");
  return v;
}
__device__ __forceinline__ void cst_u16(unsigned short* p, unsigned short v){
  asm volatile("global_store_short %0, %1, off sc0 sc1" :: "v"(p), "v"((unsigned)v) : "memory");
}
__device__ __forceinline__ void cst_f32(float* p, float v){
  asm volatile("global_store_dword %0, %1, off sc0 sc1" :: "v"(p), "v"(v) : "memory");
}
__device__ __forceinline__ void cst_u32(unsigned* p, unsigned v){
  asm volatile("global_store_dword %0, %1, off sc0 sc1" :: "v"(p), "v"(v) : "memory");
}

// ---------------------------------------------------------------------------
// Generic bf16 MFMA GEMM (prep/epilogue; unchanged - known correct).
// ---------------------------------------------------------------------------
template<int MODE>
__global__ void gemm_sw(const unsigned short* __restrict__ A,
                        const unsigned short* __restrict__ Bsw,
                        void* __restrict__ Cout,
                        int M, int N, int K, int ldc,
                        const float* __restrict__ bias)
{
  const int lane = threadIdx.x & 63;
  const int lm = lane & 15, quad = lane >> 4;
  const int nwaves = (gridDim.x * blockDim.x) >> 6;
  const int w = (blockIdx.x * blockDim.x + threadIdx.x) >> 6;
  const int m64 = M >> 6, n64 = N >> 6, KS = K >> 5;
  const int ntask = m64 * n64;
  for (int task = w; task < ntask; task += nwaves) {
    const int mt = task % m64, nt = task / m64;
    floatx4 acc[4][4];
#pragma unroll
    for (int i=0;i<4;i++)
#pragma unroll
      for(int j=0;j<4;j++) acc[i][j] = (floatx4){0.f,0.f,0.f,0.f};
    const unsigned short* Ab = A + (size_t)(mt*64 + lm) * K + quad*8;
    for (int ks=0; ks<KS; ++ks) {
      shortx8 a[4], b[4];
#pragma unroll
      for (int i=0;i<4;i++)
        a[i] = *(const shortx8*)(Ab + (size_t)i*16*K + ks*32);
#pragma unroll
      for (int j=0;j<4;j++)
        b[j] = *(const shortx8*)(Bsw + (((size_t)(nt*4+j)*KS + ks)*64 + lane)*8);
#pragma unroll
      for (int i=0;i<4;i++)
#pragma unroll
        for (int j=0;j<4;j++)
          acc[i][j] = __builtin_amdgcn_mfma_f32_16x16x32_bf16(a[i], b[j], acc[i][j], 0,0,0);
    }
#pragma unroll
    for (int i=0;i<4;i++){
#pragma unroll
      for (int j=0;j<4;j++){
        const int col = nt*64 + j*16 + lm;
        const float bv = bias ? bias[col] : 0.f;
#pragma unroll
        for (int r=0;r<4;r++){
          const int row = mt*64 + i*16 + quad*4 + r;
          const float v = acc[i][j][r] + bv;
          if (MODE==0)      ((float*)Cout)[(size_t)row*ldc + col] = v;
          else if (MODE==1) ((unsigned short*)Cout)[(size_t)row*ldc + col] = f2bf(v);
          else { const int orow = (row&63)*NS + (row>>6);
                 ((float*)Cout)[(size_t)orow*ldc + col] = v; }
        }
      }
    }
  }
}

// ---- prep kernels (unchanged) ---------------------------------------------
__global__ void conv_h(const float* __restrict__ src, unsigned short* __restrict__ dst, int n){
  for (int i = blockIdx.x*blockDim.x + threadIdx.x; i < n; i += gridDim.x*blockDim.x)
    dst[i] = f2bf(src[i]);
}

__global__ void conv_misc(const float* __restrict__ Wy2, const float* __restrict__ We2,
                          const float* __restrict__ s0, const float* __restrict__ by1,
                          const float* __restrict__ be1,
                          unsigned short* __restrict__ Wy2A, unsigned short* __restrict__ we2b,
                          unsigned short* __restrict__ s_bf, float* __restrict__ bz)
{
  int i = blockIdx.x*blockDim.x + threadIdx.x;
  if (i < 524288) Wy2A[i] = f2bf(Wy2[i]);
  else if (i < 525312) we2b[i-524288] = f2bf(We2[i-524288]);
  else if (i < 590848) s_bf[i-525312] = f2bf(s0[i-525312]);
  else if (i < 592896) { int n = i - 590848; bz[n] = (n<1024)? by1[n] : be1[n-1024]; }
}

__global__ void vbias_k(const float* __restrict__ by2,
                        const float* __restrict__ bi, const float* __restrict__ bff,
                        const float* __restrict__ bg, const float* __restrict__ bo,
                        const float* __restrict__ Wi, const float* __restrict__ Wf,
                        const float* __restrict__ Wg, const float* __restrict__ Wo,
                        float* __restrict__ vb)
{
  int i = blockIdx.x*blockDim.x + threadIdx.x;
  if (i >= 4096) return;
  int g = i >> 10, u = i & 1023;
  const float* bsrc = (g==0)?bi:(g==1)?bff:(g==2)?bg:bo;
  const float* W    = (g==0)?Wi:(g==1)?Wf:(g==2)?Wg:Wo;
  float s = bsrc[u];
  for (int tt = 0; tt < NT; ++tt) s += by2[tt] * W[(size_t)tt*NU + u];
  vb[i] = s;
}

__global__ void pack_b(const float* __restrict__ src, unsigned short* __restrict__ dst, int K, int N)
{
  const int KS = K >> 5;
  const size_t total = (size_t)K * N;
  for (size_t i = (size_t)blockIdx.x*blockDim.x + threadIdx.x; i < total;
       i += (size_t)gridDim.x*blockDim.x) {
    int j = i & 7; int lane = (i>>3) & 63; int r = (int)(i >> 9);
    int ks = r % KS; int nt = r / KS;
    int k = ks*32 + (lane>>4)*8 + j;
    int n = nt*16 + (lane&15);
    dst[i] = f2bf(src[(size_t)k*N + n]);
  }
}

__global__ void pack_a1(const float* __restrict__ Wy1, const float* __restrict__ We1,
                        unsigned short* __restrict__ dst)
{
  const int KS = 32;
  const size_t total = (size_t)1024*2048;
  for (size_t i = (size_t)blockIdx.x*blockDim.x + threadIdx.x; i < total;
       i += (size_t)gridDim.x*blockDim.x) {
    int j = i & 7; int lane = (i>>3) & 63; int r = (int)(i >> 9);
    int ks = r % KS; int nt = r / KS;
    int k = ks*32 + (lane>>4)*8 + j;
    int n = nt*16 + (lane&15);
    float v = (n < 1024) ? Wy1[(size_t)k*1024 + n]
                         : We1[(size_t)(1024+k)*1024 + (n-1024)];
    dst[i] = f2bf(v);
  }
}

__global__ void pack_wbig(const float* __restrict__ Mg,
                          const float* __restrict__ Wi, const float* __restrict__ Wf,
                          const float* __restrict__ Wg, const float* __restrict__ Wo,
                          unsigned short* __restrict__ dst)
{
  const int KS = 64;
  const size_t total = (size_t)2048*4096;
  for (size_t i = (size_t)blockIdx.x*blockDim.x + threadIdx.x; i < total;
       i += (size_t)gridDim.x*blockDim.x) {
    int j = i & 7; int lane = (i>>3) & 63; int r = (int)(i >> 9);
    int ks = r % KS; int nt = r / KS;
    int k = ks*32 + (lane>>4)*8 + j;
    int n = nt*16 + (lane&15);
    int g = n >> 10, u = n & 1023;
    float v;
    if (k < 1024) v = Mg[(size_t)g*1048576 + (size_t)k*1024 + u];
    else {
      const float* W = (g==0)?Wi:(g==1)?Wf:(g==2)?Wg:Wo;
      v = W[(size_t)(512 + k - 1024)*1024 + u];
    }
    dst[i] = f2bf(v);
  }
}

// ---- the sequential recurrence: persistent kernel, FENCE-FREE barrier ------
// v10 = v5 RESTORED VERBATIM (verified best: 12272 us). All four structural
// variants (v6 Wbig->LDS, v7 overlap+remap, v8 A1 dedup, v9 L2 prefetch)
// regressed; the law dur ~= FETCH/BW + eps puts v5 at this structure's
// measured floor: 44.9 MB/step L2-miss @ ~1.03 TB/s concurrency-capped BW,
// 3 structurally-required global barriers, per-XCD weight set at marginal
// L2 fit.
struct LoopArgs {
  unsigned short* s_all;         // (257,64,1024) bf16 t-indexed state
  unsigned short* tanh_all;      // (256,64,1024) bf16 t-indexed
  const unsigned short* A1_sw;   // weights [cached]
  const unsigned short* Wbig_sw; // weights [cached]
  const unsigned short* hproj;   // (64,256,1024) bf16  [staged to LDS pre-loop]
  const float* h;                // input h f32         [staged to VGPRs pre-loop]
  const unsigned short* we2b;    // (1024) bf16 [cached]
  float* qbuf;                   // (64,1024)   rotating [coherent]
  float* watt;                   // (64,256)    rotating [coherent]
  float* gates;                  // (64,4096)   rotating [coherent]
  const float* bz;               // (2048) [cached]
  const float* vbias;            // (4096) [cached]
  const float* be2;              // (1) [cached]
  int* bar;                      // barrier state, zeroed
};

__global__ void __launch_bounds__(1024) loop_kernel(LoopArgs A)
{
  const int tid = threadIdx.x;
  const int bid = blockIdx.x;                 // 256 blocks
  const int wid = tid >> 6;                   // 0..15
  const int lane = tid & 63;
  const int lm = lane & 15, quad = lane >> 4;

  // 128 KiB dynamic LDS: this block's hproj slice (loop-invariant).
  extern __shared__ floatx4 dynlds_v4[];
  unsigned char* const dynlds = (unsigned char*)dynlds_v4;

  // barrier layout (128B-strided counters): gcnt[16], root, gen
  int* gcnt = A.bar;
  int* root = A.bar + 16*32;
  int* genp = A.bar + 16*32 + 32;

  __shared__ float qsh[1024];        // 4 KB: this step's q for batch b3
  __shared__ floatx4 pbuf[256];      // 4 KB: K-split partial accumulators
  __shared__ float wsh[256];
  __shared__ float zparts[4];
  __shared__ floatx2 cbuf[1024];     // 8 KB

  auto gsync = [&]() {
    asm volatile("s_waitcnt vmcnt(0) lgkmcnt(0)" ::: "memory");
    __syncthreads();
    if (tid == 0) {
      int g = __hip_atomic_load(genp, __ATOMIC_RELAXED, __HIP_MEMORY_SCOPE_AGENT);
      int grp = bid >> 4;
      if (__hip_atomic_fetch_add(&gcnt[grp*32], 1, __ATOMIC_RELAXED, __HIP_MEMORY_SCOPE_AGENT) == 15) {
        __hip_atomic_store(&gcnt[grp*32], 0, __ATOMIC_RELAXED, __HIP_MEMORY_SCOPE_AGENT);
        if (__hip_atomic_fetch_add(root, 1, __ATOMIC_RELAXED, __HIP_MEMORY_SCOPE_AGENT) == 15) {
          __hip_atomic_store(root, 0, __ATOMIC_RELAXED, __HIP_MEMORY_SCOPE_AGENT);
          __hip_atomic_store(genp, g + 1, __ATOMIC_RELAXED, __HIP_MEMORY_SCOPE_AGENT);
        }
      }
      while (__hip_atomic_load(genp, __ATOMIC_RELAXED, __HIP_MEMORY_SCOPE_AGENT) == g)
        __builtin_amdgcn_s_sleep(1);
    }
    __syncthreads();
  };

  // -------- pre-loop staging: h and hproj are LOOP-INVARIANT ---------------
  const int b3 = bid >> 2;
  const int j0_blk = (bid & 3) << 6;
  const int u3 = ((bid & 3) << 8) + (tid & 127) * 2;
  const int js3 = (tid >> 7) << 5;           // 8 j-groups x 32 rows

  unsigned hreg[32];                 // h[b3, js3+jj, u3:u3+2] packed bf16x2
  {
    const float* hb = A.h + (size_t)b3*NS*NU;
#pragma unroll
    for (int jj = 0; jj < 32; ++jj) {
      const floatx2 hv = *(const floatx2*)(hb + (size_t)(js3 + jj)*NU + u3);
      hreg[jj] = ((unsigned)f2bf(hv[0])) | (((unsigned)f2bf(hv[1])) << 16);
    }
  }
  {
    // hproj[b3, j0_blk .. j0_blk+64, :] -> LDS, row r at dynlds + r*2048
    const unsigned char* hpg = (const unsigned char*)(A.hproj + ((size_t)(b3*NS + j0_blk))*NU);
#pragma unroll
    for (int it = 0; it < 8; ++it)
      *(floatx4*)(dynlds + it*16384 + tid*16) = *(const floatx4*)(hpg + it*16384 + tid*16);
  }
  // attention constants: lane's u-window split-half {8l..8l+7, 512+8l..+7}
  float w2r[16];
  if (wid >= 8) {
    const shortx8 wa = *(const shortx8*)(A.we2b + 8*lane);
    const shortx8 wb = *(const shortx8*)(A.we2b + 512 + 8*lane);
#pragma unroll
    for (int i = 0; i < 8; ++i) {
      w2r[i]   = bf2f((unsigned short)wa[i]);
      w2r[8+i] = bf2f((unsigned short)wb[i]);
    }
  }
  const float be2v = A.be2[0];
  __syncthreads();

#pragma clang loop unroll(disable)
  for (int t = 0; t < NS; ++t) {
    const unsigned short* sbase = A.s_all + (size_t)t*(NB*NU);
    // -------- P1: z2 = s @ [Wy1|We1_s] + bz -> tanh1 (bf16), q (fp32)
    // K-split over 4 waves: wave pair (w, w+2) shares task bid*2+(w&1);
    // khalf = wid>>1 covers kb {0,1} or {2,3}. Partials combined via LDS.
    {
      floatx4 accg = (floatx4){0.f,0.f,0.f,0.f};
      if (wid < 4) {
        const int task = bid*2 + (wid & 1);
        const int mt = task & 3, nt = task >> 2;
        const int kh = wid >> 1;
        floatx4 acc = (floatx4){0.f,0.f,0.f,0.f};
        const unsigned short* Ab = sbase + (mt*16 + lm)*NU + quad*8;
        for (int k = 0; k < 2; ++k) {
          const int kb = kh*2 + k;
          shortx8 a[8];
#pragma unroll
          for (int q = 0; q < 8; ++q) a[q] = *(const shortx8*)(Ab + kb*256 + q*32);
#pragma unroll
          for (int q = 0; q < 8; ++q) {
            shortx8 b = *(const shortx8*)(A.A1_sw + (((size_t)nt*32 + kb*8 + q)*64 + lane)*8);
            acc = __builtin_amdgcn_mfma_f32_16x16x32_bf16(a[q], b, acc, 0,0,0);
          }
        }
        if (wid >= 2) pbuf[(wid-2)*64 + lane] = acc; else accg = acc;
      }
      __syncthreads();
      if (wid < 2) {
        const int task = bid*2 + wid;
        const int mt = task & 3, nt = task >> 2;
        floatx4 acc = accg + pbuf[wid*64 + lane];
        const int col = nt*16 + lm;
        const float bzv = A.bz[col];
#pragma unroll
        for (int r = 0; r < 4; ++r) {
          const int row = mt*16 + quad*4 + r;
          const float v = acc[r] + bzv;
          if (col < NU) cst_u16(A.tanh_all + (size_t)t*(NB*NU) + row*NU + col, f2bf(tanhf(v)));
          else          cst_f32(A.qbuf + row*NU + (col - NU), v);
        }
      }
    }
    gsync();
    // -------- P2: gates GEMM (waves 0..7, K-split) || attention (waves 8..15)
    {
      // stage q once per block (kills the x16 qbuf LLC redundancy)
      if (tid >= 512 && tid < 768) {
        const int i = tid - 512;
        *(floatx4*)&qsh[i*4] = cld_f32x4(A.qbuf + b3*NU + i*4);
      }
      __syncthreads();
      floatx4 accg = (floatx4){0.f,0.f,0.f,0.f};
      if (wid < 8) {
        const int mt = wid & 3, nt = bid;
        const int sel = wid >> 2;            // 0: tanh-half, 1: s-half
        floatx4 acc = (floatx4){0.f,0.f,0.f,0.f};
        const int arow = mt*16 + lm;
        const unsigned short* aA =
            (sel ? sbase : A.tanh_all + (size_t)t*(NB*NU)) + arow*NU + quad*8;
        const int bofs = sel ? 32 : 0;
        for (int kb = 0; kb < 4; ++kb) {
          shortx8 a[8];
#pragma unroll
          for (int q = 0; q < 8; ++q) a[q] = *(const shortx8*)(aA + kb*256 + q*32);
#pragma unroll
          for (int q = 0; q < 8; ++q) {
            shortx8 b = *(const shortx8*)(A.Wbig_sw + (((size_t)nt*64 + bofs + kb*8 + q)*64 + lane)*8);
            acc = __builtin_amdgcn_mfma_f32_16x16x32_bf16(a[q], b, acc, 0,0,0);
          }
        }
        if (sel) pbuf[(wid-4)*64 + lane] = acc; else accg = acc;
      } else {
        // attention: 8 rows per wave, hproj from LDS, q from LDS
        const int rbase = (wid - 8) * 8;
        float qv[16];
#pragma unroll
        for (int i = 0; i < 8; ++i) {
          qv[i]   = qsh[8*lane + i];
          qv[8+i] = qsh[512 + 8*lane + i];
        }
        for (int jj = 0; jj < 8; ++jj) {
          const int rl = rbase + jj;
          const shortx8 h0 = *(const shortx8*)(dynlds + rl*2048 + lane*16);
          const shortx8 h1 = *(const shortx8*)(dynlds + rl*2048 + 1024 + lane*16);
          float dot = 0.f;
#pragma unroll
          for (int i = 0; i < 8; ++i) {
            const float x = bf2f((unsigned short)h0[i]) + qv[i];
            dot += w2r[i] * sigf(x);
          }
#pragma unroll
          for (int i = 0; i < 8; ++i) {
            const float x = bf2f((unsigned short)h1[i]) + qv[8+i];
            dot += w2r[8+i] * sigf(x);
          }
#pragma unroll
          for (int off = 32; off > 0; off >>= 1) dot += __shfl_down(dot, off, 64);
          if (lane == 0) {
            const float e = 1.f/(1.f + __expf(-(dot + be2v)));
            cst_f32(A.watt + b3*NS + (j0_blk + rl), __expf(e));
          }
        }
      }
      __syncthreads();
      if (wid < 4) {
        floatx4 acc = accg + pbuf[wid*64 + lane];
        const int col = bid*16 + lm;
        const float vb = A.vbias[col];
#pragma unroll
        for (int r = 0; r < 4; ++r) {
          const int row = (wid&3)*16 + quad*4 + r;
          cst_f32(A.gates + row*4096 + col, acc[r] + vb);
        }
      }
    }
    gsync();
    // -------- P3: softmax-normalize + context c (from hreg) + LSTM -> s_next
    {
      const int b = b3, uc = (bid & 3) << 8;
      if (tid < 256) wsh[tid] = cld_f32(A.watt + b*NS + tid);
      __syncthreads();
      if (wid < 4) {
        float z = wsh[wid*64 + lane];
#pragma unroll
        for (int off = 32; off > 0; off >>= 1) z += __shfl_down(z, off, 64);
        if (lane == 0) zparts[wid] = z;
      }
      __syncthreads();
      const float invZ = __builtin_amdgcn_rcpf(zparts[0]+zparts[1]+zparts[2]+zparts[3]);
      float c0 = 0.f, c1 = 0.f;
#pragma unroll
      for (int jj = 0; jj < 32; ++jj) {
        const unsigned hv = hreg[jj];
        const float wv = wsh[js3 + jj];
        c0 += wv * bf2f((unsigned short)(hv & 0xffffu));
        c1 += wv * bf2f((unsigned short)(hv >> 16));
      }
      cbuf[tid] = (floatx2){c0, c1};
      __syncthreads();
      if (tid < 128) {
        float cc0 = 0.f, cc1 = 0.f;
#pragma unroll
        for (int k = 0; k < 8; ++k) {
          const floatx2 v = cbuf[tid + (k << 7)];
          cc0 += v[0]; cc1 += v[1];
        }
        cc0 *= invZ; cc1 *= invZ;
        const int uu = uc + tid*2;
        const float* gp = A.gates + b*4096;
        floatx2 g4[4];
        cburst4d2(g4, gp + uu, gp + NU + uu, gp + 2*NU + uu, gp + 3*NU + uu);
        unsigned sout = 0;
#pragma unroll
        for (int p = 0; p < 2; ++p) {
          const float cx = p ? cc1 : cc0;
          const float iv = sigf(g4[0][p]);
          const float fv = sigf(g4[1][p]);
          const float gv = tanhf(g4[2][p]);
          const float ov = sigf(g4[3][p]);
          const float cn = fv*cx + iv*gv;
          const float sn = ov * tanhf(cn);
          sout |= ((unsigned)f2bf(sn)) << (16*p);
        }
        cst_u32((unsigned*)(A.s_all + (size_t)(t+1)*(NB*NU) + b*NU + uu), sout);
      }
    }
    gsync();
  }
}

// ---------------------------------------------------------------------------
extern "C" void kernel_launch(void* const* d_in, const int* in_sizes, int n_in,
                              void* d_out, int out_size, void* d_ws, size_t ws_size,
                              hipStream_t stream)
{
  const float* h   = (const float*)d_in[0];
  const float* s0  = (const float*)d_in[1];
  const float* Wy1 = (const float*)d_in[2];
  const float* by1 = (const float*)d_in[3];
  const float* Wy2 = (const float*)d_in[4];
  const float* by2 = (const float*)d_in[5];
  const float* We1 = (const float*)d_in[6];
  const float* be1 = (const float*)d_in[7];
  const float* We2 = (const float*)d_in[8];
  const float* be2 = (const float*)d_in[9];
  const float* Wf_p = (const float*)d_in[10];
  const float* bf_p = (const float*)d_in[11];
  const float* Wi_p = (const float*)d_in[12];
  const float* bi_p = (const float*)d_in[13];
  const float* Wg_p = (const float*)d_in[14];
  const float* bg_p = (const float*)d_in[15];
  const float* Wo_p = (const float*)d_in[16];
  const float* bo_p = (const float*)d_in[17];
  (void)in_sizes; (void)n_in; (void)out_size; (void)ws_size;

  char* ws = (char*)d_ws;
  size_t off = 0;
  auto alloc = [&](size_t bytes)->char*{
    char* p = ws + off; off = (off + bytes + 255) & ~(size_t)255; return p;
  };
  unsigned short* h_bf    = (unsigned short*)alloc((size_t)NB*NS*NU*2);   // 33.5 MB
  unsigned short* hproj   = (unsigned short*)alloc((size_t)NB*NS*NU*2);   // 33.5 MB
  unsigned short* tanh_all= (unsigned short*)alloc((size_t)NS*NB*NU*2);   // 33.5 MB
  unsigned short* s_all   = (unsigned short*)alloc((size_t)(NS+1)*NB*NU*2); // 33.7 MB
  unsigned short* A1_sw   = (unsigned short*)alloc((size_t)NU*2048*2);    // 4.2 MB
  unsigned short* Wbig_sw = (unsigned short*)alloc((size_t)2048*4096*2);  // 16.8 MB
  unsigned short* We1h_sw = (unsigned short*)alloc((size_t)NU*NU*2);      // 2.1 MB
  unsigned short* Wy2_sw  = (unsigned short*)alloc((size_t)NU*NT*2);      // 1.05 MB
  unsigned short* we2b = (unsigned short*)alloc(NU*2);
  float* qbuf  = (float*)alloc((size_t)NB*NU*4);
  float* watt  = (float*)alloc((size_t)NB*NS*4);
  float* gates = (float*)alloc((size_t)NB*4096*4);
  float* bz    = (float*)alloc(2048*4);
  float* vbias = (float*)alloc(4096*4);
  int*   bar   = (int*)alloc(4096);
  // prep-only buffers aliased into regions not yet written at their use time:
  float* Mg = (float*)tanh_all;                    // 16.8 MB, dead before loop
  unsigned short* Wy2A    = hproj;                 // dead before hproj GEMM
  unsigned short* Wgtop_sw= hproj + (size_t)NU*NT; // 4 MB, dead before hproj GEMM

  hipMemsetAsync(bar, 0, 4096, stream);

  conv_h<<<dim3(4096), dim3(256), 0, stream>>>(h, h_bf, NB*NS*NU);
  conv_misc<<<dim3(2316), dim3(256), 0, stream>>>(Wy2, We2, s0, by1, be1, Wy2A, we2b, s_all, bz);
  vbias_k<<<dim3(16), dim3(256), 0, stream>>>(by2, bi_p, bf_p, bg_p, bo_p,
                                              Wi_p, Wf_p, Wg_p, Wo_p, vbias);
  pack_b<<<dim3(1024), dim3(256), 0, stream>>>(We1, We1h_sw, 1024, 1024);   // We1_h
  pack_b<<<dim3(1024), dim3(256), 0, stream>>>(Wy2, Wy2_sw, 1024, 512);
  pack_b<<<dim3(512), dim3(256), 0, stream>>>(Wi_p, Wgtop_sw + 0*((size_t)NT*NU), 512, 1024);
  pack_b<<<dim3(512), dim3(256), 0, stream>>>(Wf_p, Wgtop_sw + 1*((size_t)NT*NU), 512, 1024);
  pack_b<<<dim3(512), dim3(256), 0, stream>>>(Wg_p, Wgtop_sw + 2*((size_t)NT*NU), 512, 1024);
  pack_b<<<dim3(512), dim3(256), 0, stream>>>(Wo_p, Wgtop_sw + 3*((size_t)NT*NU), 512, 1024);
  pack_a1<<<dim3(1024), dim3(256), 0, stream>>>(Wy1, We1, A1_sw);

  // Mg[g] = Wy2 @ W_g[:512]   (M=1024, N=1024, K=512)
  for (int g = 0; g < 4; ++g)
    gemm_sw<0><<<dim3(1024), dim3(256), 0, stream>>>(
        Wy2A, Wgtop_sw + (size_t)g*(NT*NU), Mg + (size_t)g*NU*NU,
        1024, 1024, 512, 1024, nullptr);
  pack_wbig<<<dim3(2048), dim3(256), 0, stream>>>(Mg, Wi_p, Wf_p, Wg_p, Wo_p, Wbig_sw);

  // h_proj = h @ We1_h -> bf16 (M=16384,N=1024,K=1024); overwrites Wy2A/Wgtop region
  gemm_sw<1><<<dim3(1024), dim3(256), 0, stream>>>(
      h_bf, We1h_sw, hproj, NB*NS, 1024, 1024, 1024, nullptr);

  // the 256-step recurrence: persistent kernel, 256 blocks (1/CU), 3 syncs/step
  // 1024 threads/block (16 waves/CU); 128 KiB dynamic LDS = hproj slice
  LoopArgs la;
  la.s_all = s_all; la.tanh_all = tanh_all; la.A1_sw = A1_sw; la.Wbig_sw = Wbig_sw;
  la.hproj = hproj; la.h = h; la.we2b = we2b;
  la.qbuf = qbuf; la.watt = watt; la.gates = gates;
  la.bz = bz; la.vbias = vbias; la.be2 = be2; la.bar = bar;
  loop_kernel<<<dim3(256), dim3(1024), 131072, stream>>>(la);

  // Y = Tanh1_all @ Wy2 + by2, remapped (t,b)->(b,t) into d_out (M=16384,N=512,K=1024)
  gemm_sw<2><<<dim3(1024), dim3(256), 0, stream>>>(
      tanh_all, Wy2_sw, d_out, NB*NS, 512, 1024, 512, by2);
}